// Round 13
// baseline (205.123 us; speedup 1.0000x reference)
//
#include <hip/hip_runtime.h>

#define C_IN 128
#define C_OUT 64
#define BN_EPS 1e-5f
#define LEAKY 0.01f

#define BSZ   256   // nodes per bucket (bucket = col >> 8)
#define NBMAX 512   // max buckets (n <= 131072)
#define CAP   6144  // pairs capacity per bucket (mean 4096, sigma ~64 -> safe)
#define CHUNKA 2048 // edges per binA block (empirical optimum: R8 bigger and
                    // R10 smaller both regress; R11 segmented-reserve regress)
#define NPART 16    // stats partial buffers (contention /16)

using bf16x8 = __attribute__((ext_vector_type(8))) __bf16;
using f32x4  = __attribute__((ext_vector_type(4))) float;

// bf16 pack/unpack (RNE pack; unpack is exact shift)
__device__ inline unsigned short f2b(float f) {
    unsigned u = __float_as_uint(f);
    return (unsigned short)((u + 0x7fffu + ((u >> 16) & 1u)) >> 16);
}
__device__ inline float b2f(unsigned short b) {
    return __uint_as_float(((unsigned)b) << 16);
}

// ---------------------------------------------------------------------------
// k_prep: fuses (1) W repack to per-lane MFMA B-fragment order, (2) bfill
// zeroing, (3) stats-partials zeroing. One launch replaces 2 memsets+wprep.
// wb[(((t*4+c)*4+q)*16 + nlo)*8 + j] = bf16(W[(c*32+q*8+j)*64 + t*16+nlo])
__global__ __launch_bounds__(256) void k_prep(const float* __restrict__ W,
                                              unsigned short* __restrict__ wb,
                                              int* __restrict__ bfill,
                                              float* __restrict__ part) {
    int idx = blockIdx.x * 256 + threadIdx.x;   // grid covers 8192
    if (idx < NBMAX) bfill[idx] = 0;
    if (idx < NPART * 128) part[idx] = 0.f;
    if (idx >= C_IN * C_OUT) return;
    int k = idx >> 6, col = idx & 63;
    int t = col >> 4, nlo = col & 15;
    int c = k >> 5, q = (k >> 3) & 3, j = k & 7;
    wb[(size_t)((((t * 4 + c) * 4 + q) * 16) + nlo) * 8 + j] = f2b(W[idx]);
}

// ---------------------------------------------------------------------------
// binA: bin edges by destination bucket WITH in-LDS chunk sort (R4 lesson:
// per-edge random 4B global scatter was 64-way address-divergent). R13: binA
// is per-block serial-phase-latency bound (VALU 1.7%, all pipes idle) -- cut
// the serial chain: (a) Hillis-Steele 512-entry scan (18 barriers) replaced
// by per-wave __shfl_up scan + 4-entry cross-wave exchange (barriers/block
// 23 -> 5); thread t owns buckets 2t,2t+1. (b) int4-vectorized edge loads.
__global__ __launch_bounds__(256) void k_binA(const int* __restrict__ rows,
                                              const int* __restrict__ cols,
                                              int* __restrict__ bfill,
                                              unsigned* __restrict__ pairs,
                                              int nE, int NB) {
    __shared__ int hist[NBMAX];
    __shared__ int base[NBMAX];    // global reserved base per bucket
    __shared__ int lstart[NBMAX];  // local (in-chunk) exclusive start
    __shared__ int cursor[NBMAX];
    __shared__ unsigned lpair[CHUNKA];
    __shared__ unsigned short lbkt[CHUNKA];
    __shared__ unsigned lsorted[CHUNKA];
    __shared__ unsigned short lsbkt[CHUNKA];
    __shared__ int wsum[4];        // per-wave scan partials
    int t = threadIdx.x;
    int lane = t & 63, wv = t >> 6;
    int chunk = blockIdx.x * CHUNKA;
    int cnt = min(chunk + CHUNKA, nE) - chunk;

    hist[t] = 0; hist[t + 256] = 0;
    __syncthreads();                                   // B1

    // phase 1: load once (int4-vectorized), stage packed pair+bucket, hist
    int cnt4 = cnt >> 2;
    for (int i4 = t; i4 < cnt4; i4 += 256) {
        int4 c4 = ((const int4*)(cols + chunk))[i4];
        int4 r4 = ((const int4*)(rows + chunk))[i4];
        #pragma unroll
        for (int e = 0; e < 4; ++e) {
            int c = (&c4.x)[e];
            unsigned r = (unsigned)((&r4.x)[e]);
            int b = c >> 8;
            lpair[i4 * 4 + e] = ((unsigned)(c & (BSZ - 1)) << 24) | r;
            lbkt[i4 * 4 + e] = (unsigned short)b;
            atomicAdd(&hist[b], 1);
        }
    }
    for (int i = (cnt4 << 2) + t; i < cnt; i += 256) {  // tail (generality)
        int c = cols[chunk + i];
        unsigned r = (unsigned)rows[chunk + i];
        int b = c >> 8;
        lpair[i] = ((unsigned)(c & (BSZ - 1)) << 24) | r;
        lbkt[i] = (unsigned short)b;
        atomicAdd(&hist[b], 1);
    }
    __syncthreads();                                   // B2

    // phase 2: global reserve (latency overlaps phases 3-4; base used in 5)
    int b0 = 2 * t, b1 = 2 * t + 1;
    int h0 = hist[b0], h1 = hist[b1];
    if (b0 < NB && h0) base[b0] = atomicAdd(&bfill[b0], h0);
    if (b1 < NB && h1) base[b1] = atomicAdd(&bfill[b1], h1);

    // phase 3: barrier-free wave scan. thread sum s covers entries b0,b1;
    // inclusive shfl_up scan within wave, wave totals exchanged via LDS.
    int s = h0 + h1;
    int inc = s;
    #pragma unroll
    for (int off = 1; off < 64; off <<= 1) {
        int x = __shfl_up(inc, off);
        if (lane >= off) inc += x;
    }
    if (lane == 63) wsum[wv] = inc;
    __syncthreads();                                   // B3
    int woff = 0;
    #pragma unroll
    for (int w = 0; w < 4; ++w) woff += (w < wv) ? wsum[w] : 0;
    int excl = woff + inc - s;     // exclusive prefix of entry b0
    lstart[b0] = excl;       lstart[b1] = excl + h0;
    cursor[b0] = excl;       cursor[b1] = excl + h0;
    __syncthreads();                                   // B4

    // phase 4: reorder into bucket-sorted LDS order
    for (int i = t; i < cnt; i += 256) {
        int b = lbkt[i];
        int pos = atomicAdd(&cursor[b], 1);
        lsorted[pos] = lpair[i];
        lsbkt[pos] = (unsigned short)b;
    }
    __syncthreads();                                   // B5

    // phase 5: write out sorted -> consecutive addrs within each bucket run
    for (int i = t; i < cnt; i += 256) {
        int b = lsbkt[i];
        int off = base[b] + (i - lstart[b]);
        if (off < CAP)  // defensive; never hit
            pairs[(size_t)b * CAP + off] = lsorted[i];
    }
}

// ---------------------------------------------------------------------------
// binB: one block per bucket, sorts its pairs region IN PLACE (stages all of
// it in LDS before the first write -> srcs aliases pairs). R12-proven: 512
// threads (binB is occupancy-starved; wider block halves per-block latency).
__global__ __launch_bounds__(512) void k_binB(const int* __restrict__ bfill,
                                              const unsigned* __restrict__ pairs,
                                              int2* __restrict__ pd,
                                              int* __restrict__ srcs, int n) {
    __shared__ unsigned rowbuf[CAP];
    __shared__ int sorted[CAP];
    __shared__ int histL[BSZ];
    __shared__ int scanL[BSZ];
    int b = blockIdx.x;
    int t = threadIdx.x;
    int cnt = min(bfill[b], CAP);
    const unsigned* reg = pairs + (size_t)b * CAP;

    if (t < BSZ) histL[t] = 0;
    __syncthreads();
    for (int i = t; i < cnt; i += 512) {
        unsigned p = reg[i];          // all reads of the region happen here,
        rowbuf[i] = p;                // before any write below (in-place safe)
        atomicAdd(&histL[p >> 24], 1);
    }
    __syncthreads();

    int hv = (t < BSZ) ? histL[t] : 0;
    if (t < BSZ) scanL[t] = hv;
    __syncthreads();
    for (int off = 1; off < BSZ; off <<= 1) {
        int x = (t < BSZ && t >= off) ? scanL[t - off] : 0;
        __syncthreads();
        if (t < BSZ) scanL[t] += x;
        __syncthreads();
    }
    int my_start = (t < BSZ) ? (scanL[t] - hv) : 0;  // exclusive within bucket

    int s0 = b * CAP;              // fixed per-bucket region: no global scan
    int node = (b << 8) + t;
    if (t < BSZ && node < n) pd[node] = make_int2(s0 + my_start, hv);
    __syncthreads();
    if (t < BSZ) histL[t] = my_start;  // cursor
    __syncthreads();
    for (int i = t; i < cnt; i += 512) {
        unsigned p = rowbuf[i];
        int pos = atomicAdd(&histL[p >> 24], 1);
        sorted[pos] = (int)(p & 0xFFFFFFu);
    }
    __syncthreads();
    for (int i = t; i < cnt; i += 512)
        srcs[s0 + i] = sorted[i];
}

// ---------------------------------------------------------------------------
// K3: xwsb = bf16( (x @ W) * rsqrt(deg+1) ) via MFMA 16x16x32 bf16, NO LDS.
// One wave = 16 nodes x 64 channels. B-frags vector-loaded from wb (L2-hot).
// Layouts (m89-verified): A[m=lane&15][k=quad*8+j], B[k=quad*8+j][n=lane&15],
// D: col=lane&15, row=quad*4+reg.
__global__ __launch_bounds__(256) void k_gemm(const float* __restrict__ x,
                                              const unsigned short* __restrict__ wb,
                                              const int2* __restrict__ pd,
                                              unsigned short* __restrict__ xwsb, int n) {
    const int lane = threadIdx.x & 63;
    const int wave = threadIdx.x >> 6;
    const int base = (blockIdx.x * 4 + wave) * 16;
    if (base >= n) return;

    const int nlo  = lane & 15;
    const int quad = lane >> 4;

    const bf16x8* Wv = (const bf16x8*)wb;
    bf16x8 Bf[4][4];
    #pragma unroll
    for (int t = 0; t < 4; ++t)
        #pragma unroll
        for (int c = 0; c < 4; ++c)
            Bf[t][c] = Wv[((t * 4 + c) * 4 + quad) * 16 + nlo];

    f32x4 acc[4] = {};
    int m = base + nlo;
    const float* xrow = x + (size_t)(m < n ? m : n - 1) * C_IN;

    #pragma unroll
    for (int c = 0; c < 4; ++c) {
        float4 a0 = *(const float4*)&xrow[c * 32 + quad * 8];
        float4 a1 = *(const float4*)&xrow[c * 32 + quad * 8 + 4];
        bf16x8 Af;
        Af[0] = (__bf16)a0.x; Af[1] = (__bf16)a0.y;
        Af[2] = (__bf16)a0.z; Af[3] = (__bf16)a0.w;
        Af[4] = (__bf16)a1.x; Af[5] = (__bf16)a1.y;
        Af[6] = (__bf16)a1.z; Af[7] = (__bf16)a1.w;
        #pragma unroll
        for (int t = 0; t < 4; ++t)
            acc[t] = __builtin_amdgcn_mfma_f32_16x16x32_bf16(Af, Bf[t][c], acc[t], 0, 0, 0);
    }

    #pragma unroll
    for (int r = 0; r < 4; ++r) {
        int node = base + quad * 4 + r;
        if (node < n) {
            float dn = rsqrtf((float)(pd[node].y + 1));
            #pragma unroll
            for (int t = 0; t < 4; ++t)
                xwsb[(size_t)node * C_OUT + t * 16 + nlo] = f2b(acc[t][r] * dn);
        }
    }
}

// ---------------------------------------------------------------------------
// K6: gather-aggregate, EIGHT nodes per wave (one per 8-lane octant) +
// fused BN-stats. Non-persistent, no loop-carried prefetch (R2/R3 lesson).
// lane=(o,s): o=lane>>3 selects the node, s=lane&7 a 16B slice (8 bf16 ch)
// -> 8 lanes cover the whole 128B row. R9-proven; gather is at its
// random-access roofline (~85MB L2-miss @ ~2.8TB/s) -- do not touch.
#define ACC8(d) do { \
    acc[0] += __uint_as_float((d).x << 16); \
    acc[1] += __uint_as_float((d).x & 0xffff0000u); \
    acc[2] += __uint_as_float((d).y << 16); \
    acc[3] += __uint_as_float((d).y & 0xffff0000u); \
    acc[4] += __uint_as_float((d).z << 16); \
    acc[5] += __uint_as_float((d).z & 0xffff0000u); \
    acc[6] += __uint_as_float((d).w << 16); \
    acc[7] += __uint_as_float((d).w & 0xffff0000u); } while (0)

__global__ __launch_bounds__(256) void k_gather(const int2* __restrict__ pd,
                                                const int* __restrict__ srcs,
                                                const unsigned short* __restrict__ xwsb,
                                                float* __restrict__ out,
                                                float* __restrict__ part, int n) {
    __shared__ float sredS[32][65];
    __shared__ float sredQ[32][65];
    int lane = threadIdx.x & 63;
    int wv   = threadIdx.x >> 6;
    int s    = lane & 7;   // slice: owns channels s*8 .. s*8+7
    int o    = lane >> 3;  // octant: node within wave
    const uint4* xw16 = (const uint4*)xwsb;  // 1 uint4 = 8 bf16; row = 8 uint4

    int node = blockIdx.x * 32 + wv * 8 + o;
    bool active = node < n;

    int2 p = active ? pd[node] : make_int2(0, 0);
    int dg = p.y;
    float dn = rsqrtf((float)(dg + 1));
    // self-loop term: this lane's 8 channels of own row (16B aligned)
    uint4 selfu = active ? xw16[(size_t)node * 8 + s] : make_uint4(0, 0, 0, 0);

    float acc[8] = {0.f, 0.f, 0.f, 0.f, 0.f, 0.f, 0.f, 0.f};

    int sv0 = (active && s < dg) ? srcs[p.x + s] : 0;
    int sv1 = (active && 8 + s < dg) ? srcs[p.x + 8 + s] : 0;
    for (int b2 = 0;;) {
        int m = dg - b2;   // octants beyond m masked by the guards
        #pragma unroll
        for (int j = 0; j < 8; ++j) {
            int src = __shfl(sv0, (o << 3) + j);  // within own octant
            if (j < m) {
                uint4 d = xw16[((size_t)src << 3) + s];
                ACC8(d);
            }
        }
        #pragma unroll
        for (int j = 0; j < 8; ++j) {
            int src = __shfl(sv1, (o << 3) + j);
            if (8 + j < m) {
                uint4 d = xw16[((size_t)src << 3) + s];
                ACC8(d);
            }
        }
        b2 += 16;
        if (b2 >= dg) break;  // deg>16: ~47% of nodes take a 2nd pass
        sv0 = (s < dg - b2) ? srcs[p.x + b2 + s] : 0;
        sv1 = (8 + s < dg - b2) ? srcs[p.x + b2 + 8 + s] : 0;
    }

    // finish: add self, scale by dis[col] (no cross-lane reduce needed)
    float v[8];
    unsigned su[4] = {selfu.x, selfu.y, selfu.z, selfu.w};
    #pragma unroll
    for (int k = 0; k < 4; ++k) {
        v[2 * k]     = (acc[2 * k]     + __uint_as_float(su[k] << 16)) * dn;
        v[2 * k + 1] = (acc[2 * k + 1] + __uint_as_float(su[k] & 0xffff0000u)) * dn;
    }
    if (active) {
        float4* op = (float4*)&out[(size_t)node * C_OUT + s * 8];
        op[0] = make_float4(v[0], v[1], v[2], v[3]);
        op[1] = make_float4(v[4], v[5], v[6], v[7]);
    }
    // inactive octants: dg=0 -> acc=0, selfu=0, dn=1 -> v=0, safe for stats

    // fused BN stats: slot=(wave,octant); unique (slot,channel) writer;
    // stride 65 -> conflict-free banks
    int slot = wv * 8 + o;
    #pragma unroll
    for (int k = 0; k < 8; ++k) {
        sredS[slot][s * 8 + k] = v[k];
        sredQ[slot][s * 8 + k] = v[k] * v[k];
    }
    __syncthreads();
    int t = threadIdx.x;
    if (t < 128) {
        int cc = t & 63;
        float a = 0.f;
        if (t < 64) {
            #pragma unroll
            for (int j = 0; j < 32; ++j) a += sredS[j][cc];
        } else {
            #pragma unroll
            for (int j = 0; j < 32; ++j) a += sredQ[j][cc];
        }
        atomicAdd(&part[(blockIdx.x & (NPART - 1)) * 128 + t], a);
    }
}

// ---------------------------------------------------------------------------
// K8: BN normalize + LeakyReLU, float4, in-place. Prologue reduces the
// 16x128 stats partials in LDS (8KB, L2-broadcast-hot) -> kills k_stats.
__global__ __launch_bounds__(256) void k_final(const float* __restrict__ part,
                                               const float* __restrict__ gamma,
                                               const float* __restrict__ beta,
                                               float* __restrict__ out, int n) {
    __shared__ float lp[NPART * 128];
    __shared__ float tot[128];
    int t = threadIdx.x;
    #pragma unroll
    for (int r = 0; r < NPART * 128 / 256; ++r)
        lp[t + r * 256] = part[t + r * 256];
    __syncthreads();
    if (t < 128) {
        float a = 0.f;
        #pragma unroll
        for (int j = 0; j < NPART; ++j) a += lp[j * 128 + t];
        tot[t] = a;
    }
    __syncthreads();

    int gid = blockIdx.x * 256 + t;
    int total4 = n * (C_OUT / 4);
    if (gid >= total4) return;
    int c4 = (gid & 15) * 4;
    float inv_n = 1.0f / (float)n;
    float4 g4 = *(const float4*)&gamma[c4];
    float4 b4 = *(const float4*)&beta[c4];
    float4 v = ((const float4*)out)[gid];

    float m, var, k, y;
    m = tot[c4 + 0] * inv_n; var = tot[64 + c4 + 0] * inv_n - m * m;
    k = rsqrtf(var + BN_EPS) * g4.x;
    y = (v.x - m) * k + b4.x; v.x = y >= 0.f ? y : LEAKY * y;
    m = tot[c4 + 1] * inv_n; var = tot[64 + c4 + 1] * inv_n - m * m;
    k = rsqrtf(var + BN_EPS) * g4.y;
    y = (v.y - m) * k + b4.y; v.y = y >= 0.f ? y : LEAKY * y;
    m = tot[c4 + 2] * inv_n; var = tot[64 + c4 + 2] * inv_n - m * m;
    k = rsqrtf(var + BN_EPS) * g4.z;
    y = (v.z - m) * k + b4.z; v.z = y >= 0.f ? y : LEAKY * y;
    m = tot[c4 + 3] * inv_n; var = tot[64 + c4 + 3] * inv_n - m * m;
    k = rsqrtf(var + BN_EPS) * g4.w;
    y = (v.w - m) * k + b4.w; v.w = y >= 0.f ? y : LEAKY * y;

    ((float4*)out)[gid] = v;
}

// ---------------------------------------------------------------------------
extern "C" void kernel_launch(void* const* d_in, const int* in_sizes, int n_in,
                              void* d_out, int out_size, void* d_ws, size_t ws_size,
                              hipStream_t stream) {
    const float* x     = (const float*)d_in[0];
    const int*   ei    = (const int*)d_in[1];
    const float* W     = (const float*)d_in[2];
    // d_in[3] = b: cancels in BatchNorm, unused.
    const float* gamma = (const float*)d_in[4];
    const float* beta  = (const float*)d_in[5];
    float* out = (float*)d_out;

    int n  = in_sizes[0] / C_IN;
    int nE = in_sizes[1] / 2;
    const int* rows = ei;
    const int* cols = ei + nE;
    int NB = (n + BSZ - 1) / BSZ;  // 391 for n=100k (<= NBMAX)

    // ws layout (srcs ALIASES pairs: binB sorts in place):
    // pd[n] int2 | xwsb[n*64] ushort | pairs/srcs[NB*CAP] | bfill[NBMAX] |
    // part[NPART*128] f32 | wb[8192] ushort
    int2* pd = (int2*)d_ws;
    unsigned short* xwsb = (unsigned short*)(pd + n);
    unsigned* pairs = (unsigned*)(xwsb + (size_t)n * C_OUT);
    int* srcs = (int*)pairs;
    int* bfill = (int*)(pairs + (size_t)NB * CAP);
    float* part = (float*)(bfill + NBMAX);
    unsigned short* wb = (unsigned short*)(part + NPART * 128);

    // 6 graph nodes: prep, binA, binB, gemm, gather(+stats), final
    k_prep<<<(C_IN * C_OUT + 255) / 256, 256, 0, stream>>>(W, wb, bfill, part);
    k_binA<<<(nE + CHUNKA - 1) / CHUNKA, 256, 0, stream>>>(rows, cols, bfill, pairs, nE, NB);
    k_binB<<<NB, 512, 0, stream>>>(bfill, pairs, pd, srcs, n);
    k_gemm<<<(n + 63) / 64, 256, 0, stream>>>(x, wb, pd, xwsb, n);
    k_gather<<<(n + 31) / 32, 256, 0, stream>>>(pd, srcs, xwsb, out, part, n);
    k_final<<<(n * (C_OUT / 4) + 255) / 256, 256, 0, stream>>>(part, gamma, beta, out, n);
}

// Round 15
// 191.876 us; speedup vs baseline: 1.0690x; 1.0690x over previous
//
#include <hip/hip_runtime.h>

#define C_IN 128
#define C_OUT 64
#define BN_EPS 1e-5f
#define LEAKY 0.01f

#define BSZ   256   // nodes per bucket (bucket = col >> 8)
#define NBMAX 512   // max buckets (n <= 131072)
#define CAP   6144  // pairs capacity per bucket (mean 4096, sigma ~64 -> safe)
#define CHUNKA 2048 // edges per binA block (empirical optimum across R8/R10/
                    // R11/R13: bigger, smaller, segmented-reserve, and
                    // barrier-reduced variants all regress)
#define NPART 16    // stats partial buffers (contention /16)

using bf16x8 = __attribute__((ext_vector_type(8))) __bf16;
using f32x4  = __attribute__((ext_vector_type(4))) float;

// bf16 pack/unpack (RNE pack; unpack is exact shift)
__device__ inline unsigned short f2b(float f) {
    unsigned u = __float_as_uint(f);
    return (unsigned short)((u + 0x7fffu + ((u >> 16) & 1u)) >> 16);
}
__device__ inline float b2f(unsigned short b) {
    return __uint_as_float(((unsigned)b) << 16);
}

// ---------------------------------------------------------------------------
// k_prep: fuses (1) W repack to per-lane MFMA B-fragment order, (2) bfill
// zeroing, (3) stats-partials zeroing. One launch replaces 2 memsets+wprep.
// wb[(((t*4+c)*4+q)*16 + nlo)*8 + j] = bf16(W[(c*32+q*8+j)*64 + t*16+nlo])
__global__ __launch_bounds__(256) void k_prep(const float* __restrict__ W,
                                              unsigned short* __restrict__ wb,
                                              int* __restrict__ bfill,
                                              float* __restrict__ part) {
    int idx = blockIdx.x * 256 + threadIdx.x;   // grid covers 8192
    if (idx < NBMAX) bfill[idx] = 0;
    if (idx < NPART * 128) part[idx] = 0.f;
    if (idx >= C_IN * C_OUT) return;
    int k = idx >> 6, col = idx & 63;
    int t = col >> 4, nlo = col & 15;
    int c = k >> 5, q = (k >> 3) & 3, j = k & 7;
    wb[(size_t)((((t * 4 + c) * 4 + q) * 16) + nlo) * 8 + j] = f2b(W[idx]);
}

// ---------------------------------------------------------------------------
// binA: bin edges by destination bucket WITH in-LDS chunk sort (R4 lesson:
// per-edge random 4B global scatter was 64-way address-divergent). R7/R12
// form is the empirical optimum (5 alternative theories falsified). Do not
// touch: residual cost is intrinsic to the two-pass out-of-core bucket sort.
__global__ __launch_bounds__(256) void k_binA(const int* __restrict__ rows,
                                              const int* __restrict__ cols,
                                              int* __restrict__ bfill,
                                              unsigned* __restrict__ pairs,
                                              int nE, int NB) {
    __shared__ int hist[NBMAX];
    __shared__ int base[NBMAX];    // global reserved base per bucket
    __shared__ int lstart[NBMAX];  // local (in-chunk) exclusive start
    __shared__ int cursor[NBMAX];
    __shared__ unsigned lpair[CHUNKA];
    __shared__ unsigned short lbkt[CHUNKA];
    __shared__ unsigned lsorted[CHUNKA];
    __shared__ unsigned short lsbkt[CHUNKA];
    int t = threadIdx.x;
    int chunk = blockIdx.x * CHUNKA;
    int cnt = min(chunk + CHUNKA, nE) - chunk;

    hist[t] = 0; hist[t + 256] = 0;
    __syncthreads();

    // phase 1: load once, stage packed pair + bucket, LDS histogram
    for (int i = t; i < cnt; i += 256) {
        int c = cols[chunk + i];
        unsigned r = (unsigned)rows[chunk + i];
        int b = c >> 8;
        lpair[i] = ((unsigned)(c & (BSZ - 1)) << 24) | r;
        lbkt[i] = (unsigned short)b;
        atomicAdd(&hist[b], 1);
    }
    __syncthreads();

    // phase 2: global reserve; seed local scan
    int h0 = hist[t], h1 = hist[t + 256];
    if (t < NB && h0) base[t] = atomicAdd(&bfill[t], h0);
    if (t + 256 < NB && h1) base[t + 256] = atomicAdd(&bfill[t + 256], h1);
    lstart[t] = h0; lstart[t + 256] = h1;
    __syncthreads();
    // phase 3: Hillis-Steele inclusive scan over 512 entries (2 per thread)
    for (int off = 1; off < 512; off <<= 1) {
        int a = (t >= off) ? lstart[t - off] : 0;
        int bb = lstart[t + 256 - off];   // t+256-off >= 0 always (off<=256)
        __syncthreads();
        lstart[t] += a; lstart[t + 256] += bb;
        __syncthreads();
    }
    int s0 = lstart[t] - h0, s1 = lstart[t + 256] - h1;  // own-entry only
    lstart[t] = s0; lstart[t + 256] = s1;                // inclusive->exclusive
    cursor[t] = s0; cursor[t + 256] = s1;
    __syncthreads();

    // phase 4: reorder into bucket-sorted LDS order
    for (int i = t; i < cnt; i += 256) {
        int b = lbkt[i];
        int pos = atomicAdd(&cursor[b], 1);
        lsorted[pos] = lpair[i];
        lsbkt[pos] = (unsigned short)b;
    }
    __syncthreads();

    // phase 5: write out sorted -> consecutive addrs within each bucket run
    for (int i = t; i < cnt; i += 256) {
        int b = lsbkt[i];
        int off = base[b] + (i - lstart[b]);
        if (off < CAP)  // defensive; never hit
            pairs[(size_t)b * CAP + off] = lsorted[i];
    }
}

// ---------------------------------------------------------------------------
// binB: one block per bucket, sorts its pairs region IN PLACE (stages all of
// it in LDS before the first write -> srcs aliases pairs). R12-proven: 512
// threads (binB is occupancy-starved; wider block halves per-block latency).
__global__ __launch_bounds__(512) void k_binB(const int* __restrict__ bfill,
                                              const unsigned* __restrict__ pairs,
                                              int2* __restrict__ pd,
                                              int* __restrict__ srcs, int n) {
    __shared__ unsigned rowbuf[CAP];
    __shared__ int sorted[CAP];
    __shared__ int histL[BSZ];
    __shared__ int scanL[BSZ];
    int b = blockIdx.x;
    int t = threadIdx.x;
    int cnt = min(bfill[b], CAP);
    const unsigned* reg = pairs + (size_t)b * CAP;

    if (t < BSZ) histL[t] = 0;
    __syncthreads();
    for (int i = t; i < cnt; i += 512) {
        unsigned p = reg[i];          // all reads of the region happen here,
        rowbuf[i] = p;                // before any write below (in-place safe)
        atomicAdd(&histL[p >> 24], 1);
    }
    __syncthreads();

    int hv = (t < BSZ) ? histL[t] : 0;
    if (t < BSZ) scanL[t] = hv;
    __syncthreads();
    for (int off = 1; off < BSZ; off <<= 1) {
        int x = (t < BSZ && t >= off) ? scanL[t - off] : 0;
        __syncthreads();
        if (t < BSZ) scanL[t] += x;
        __syncthreads();
    }
    int my_start = (t < BSZ) ? (scanL[t] - hv) : 0;  // exclusive within bucket

    int s0 = b * CAP;              // fixed per-bucket region: no global scan
    int node = (b << 8) + t;
    if (t < BSZ && node < n) pd[node] = make_int2(s0 + my_start, hv);
    __syncthreads();
    if (t < BSZ) histL[t] = my_start;  // cursor
    __syncthreads();
    for (int i = t; i < cnt; i += 512) {
        unsigned p = rowbuf[i];
        int pos = atomicAdd(&histL[p >> 24], 1);
        sorted[pos] = (int)(p & 0xFFFFFFu);
    }
    __syncthreads();
    for (int i = t; i < cnt; i += 512)
        srcs[s0 + i] = sorted[i];
}

// ---------------------------------------------------------------------------
// K3: xwsb = bf16( (x @ W) * rsqrt(deg+1) ) via MFMA 16x16x32 bf16, NO LDS.
// One wave = 16 nodes x 64 channels. B-frags vector-loaded from wb (L2-hot).
// Layouts (m89-verified): A[m=lane&15][k=quad*8+j], B[k=quad*8+j][n=lane&15],
// D: col=lane&15, row=quad*4+reg.
__global__ __launch_bounds__(256) void k_gemm(const float* __restrict__ x,
                                              const unsigned short* __restrict__ wb,
                                              const int2* __restrict__ pd,
                                              unsigned short* __restrict__ xwsb, int n) {
    const int lane = threadIdx.x & 63;
    const int wave = threadIdx.x >> 6;
    const int base = (blockIdx.x * 4 + wave) * 16;
    if (base >= n) return;

    const int nlo  = lane & 15;
    const int quad = lane >> 4;

    const bf16x8* Wv = (const bf16x8*)wb;
    bf16x8 Bf[4][4];
    #pragma unroll
    for (int t = 0; t < 4; ++t)
        #pragma unroll
        for (int c = 0; c < 4; ++c)
            Bf[t][c] = Wv[((t * 4 + c) * 4 + quad) * 16 + nlo];

    f32x4 acc[4] = {};
    int m = base + nlo;
    const float* xrow = x + (size_t)(m < n ? m : n - 1) * C_IN;

    #pragma unroll
    for (int c = 0; c < 4; ++c) {
        float4 a0 = *(const float4*)&xrow[c * 32 + quad * 8];
        float4 a1 = *(const float4*)&xrow[c * 32 + quad * 8 + 4];
        bf16x8 Af;
        Af[0] = (__bf16)a0.x; Af[1] = (__bf16)a0.y;
        Af[2] = (__bf16)a0.z; Af[3] = (__bf16)a0.w;
        Af[4] = (__bf16)a1.x; Af[5] = (__bf16)a1.y;
        Af[6] = (__bf16)a1.z; Af[7] = (__bf16)a1.w;
        #pragma unroll
        for (int t = 0; t < 4; ++t)
            acc[t] = __builtin_amdgcn_mfma_f32_16x16x32_bf16(Af, Bf[t][c], acc[t], 0, 0, 0);
    }

    #pragma unroll
    for (int r = 0; r < 4; ++r) {
        int node = base + quad * 4 + r;
        if (node < n) {
            float dn = rsqrtf((float)(pd[node].y + 1));
            #pragma unroll
            for (int t = 0; t < 4; ++t)
                xwsb[(size_t)node * C_OUT + t * 16 + nlo] = f2b(acc[t][r] * dn);
        }
    }
}

// ---------------------------------------------------------------------------
// K6: gather-aggregate, EIGHT nodes per wave (one per 8-lane octant) +
// fused BN-stats. Non-persistent, no loop-carried prefetch (R2/R3 lesson).
// lane=(o,s): o=lane>>3 selects the node, s=lane&7 a 16B slice (8 bf16 ch)
// -> 8 lanes cover the whole 128B row. R9-proven; gather is at its
// random-access roofline (~85MB L2-miss @ ~2.8TB/s) -- do not touch.
#define ACC8(d) do { \
    acc[0] += __uint_as_float((d).x << 16); \
    acc[1] += __uint_as_float((d).x & 0xffff0000u); \
    acc[2] += __uint_as_float((d).y << 16); \
    acc[3] += __uint_as_float((d).y & 0xffff0000u); \
    acc[4] += __uint_as_float((d).z << 16); \
    acc[5] += __uint_as_float((d).z & 0xffff0000u); \
    acc[6] += __uint_as_float((d).w << 16); \
    acc[7] += __uint_as_float((d).w & 0xffff0000u); } while (0)

__global__ __launch_bounds__(256) void k_gather(const int2* __restrict__ pd,
                                                const int* __restrict__ srcs,
                                                const unsigned short* __restrict__ xwsb,
                                                float* __restrict__ out,
                                                float* __restrict__ part, int n) {
    __shared__ float sredS[32][65];
    __shared__ float sredQ[32][65];
    int lane = threadIdx.x & 63;
    int wv   = threadIdx.x >> 6;
    int s    = lane & 7;   // slice: owns channels s*8 .. s*8+7
    int o    = lane >> 3;  // octant: node within wave
    const uint4* xw16 = (const uint4*)xwsb;  // 1 uint4 = 8 bf16; row = 8 uint4

    int node = blockIdx.x * 32 + wv * 8 + o;
    bool active = node < n;

    int2 p = active ? pd[node] : make_int2(0, 0);
    int dg = p.y;
    float dn = rsqrtf((float)(dg + 1));
    // self-loop term: this lane's 8 channels of own row (16B aligned)
    uint4 selfu = active ? xw16[(size_t)node * 8 + s] : make_uint4(0, 0, 0, 0);

    float acc[8] = {0.f, 0.f, 0.f, 0.f, 0.f, 0.f, 0.f, 0.f};

    int sv0 = (active && s < dg) ? srcs[p.x + s] : 0;
    int sv1 = (active && 8 + s < dg) ? srcs[p.x + 8 + s] : 0;
    for (int b2 = 0;;) {
        int m = dg - b2;   // octants beyond m masked by the guards
        #pragma unroll
        for (int j = 0; j < 8; ++j) {
            int src = __shfl(sv0, (o << 3) + j);  // within own octant
            if (j < m) {
                uint4 d = xw16[((size_t)src << 3) + s];
                ACC8(d);
            }
        }
        #pragma unroll
        for (int j = 0; j < 8; ++j) {
            int src = __shfl(sv1, (o << 3) + j);
            if (8 + j < m) {
                uint4 d = xw16[((size_t)src << 3) + s];
                ACC8(d);
            }
        }
        b2 += 16;
        if (b2 >= dg) break;  // deg>16: ~47% of nodes take a 2nd pass
        sv0 = (s < dg - b2) ? srcs[p.x + b2 + s] : 0;
        sv1 = (8 + s < dg - b2) ? srcs[p.x + b2 + 8 + s] : 0;
    }

    // finish: add self, scale by dis[col] (no cross-lane reduce needed)
    float v[8];
    unsigned su[4] = {selfu.x, selfu.y, selfu.z, selfu.w};
    #pragma unroll
    for (int k = 0; k < 4; ++k) {
        v[2 * k]     = (acc[2 * k]     + __uint_as_float(su[k] << 16)) * dn;
        v[2 * k + 1] = (acc[2 * k + 1] + __uint_as_float(su[k] & 0xffff0000u)) * dn;
    }
    if (active) {
        float4* op = (float4*)&out[(size_t)node * C_OUT + s * 8];
        op[0] = make_float4(v[0], v[1], v[2], v[3]);
        op[1] = make_float4(v[4], v[5], v[6], v[7]);
    }
    // inactive octants: dg=0 -> acc=0, selfu=0, dn=1 -> v=0, safe for stats

    // fused BN stats: slot=(wave,octant); unique (slot,channel) writer;
    // stride 65 -> conflict-free banks
    int slot = wv * 8 + o;
    #pragma unroll
    for (int k = 0; k < 8; ++k) {
        sredS[slot][s * 8 + k] = v[k];
        sredQ[slot][s * 8 + k] = v[k] * v[k];
    }
    __syncthreads();
    int t = threadIdx.x;
    if (t < 128) {
        int cc = t & 63;
        float a = 0.f;
        if (t < 64) {
            #pragma unroll
            for (int j = 0; j < 32; ++j) a += sredS[j][cc];
        } else {
            #pragma unroll
            for (int j = 0; j < 32; ++j) a += sredQ[j][cc];
        }
        atomicAdd(&part[(blockIdx.x & (NPART - 1)) * 128 + t], a);
    }
}

// ---------------------------------------------------------------------------
// K8: BN normalize + LeakyReLU, float4, in-place. Prologue reduces the
// 16x128 stats partials in LDS (8KB, L2-broadcast-hot) -> kills k_stats.
__global__ __launch_bounds__(256) void k_final(const float* __restrict__ part,
                                               const float* __restrict__ gamma,
                                               const float* __restrict__ beta,
                                               float* __restrict__ out, int n) {
    __shared__ float lp[NPART * 128];
    __shared__ float tot[128];
    int t = threadIdx.x;
    #pragma unroll
    for (int r = 0; r < NPART * 128 / 256; ++r)
        lp[t + r * 256] = part[t + r * 256];
    __syncthreads();
    if (t < 128) {
        float a = 0.f;
        #pragma unroll
        for (int j = 0; j < NPART; ++j) a += lp[j * 128 + t];
        tot[t] = a;
    }
    __syncthreads();

    int gid = blockIdx.x * 256 + t;
    int total4 = n * (C_OUT / 4);
    if (gid >= total4) return;
    int c4 = (gid & 15) * 4;
    float inv_n = 1.0f / (float)n;
    float4 g4 = *(const float4*)&gamma[c4];
    float4 b4 = *(const float4*)&beta[c4];
    float4 v = ((const float4*)out)[gid];

    float m, var, k, y;
    m = tot[c4 + 0] * inv_n; var = tot[64 + c4 + 0] * inv_n - m * m;
    k = rsqrtf(var + BN_EPS) * g4.x;
    y = (v.x - m) * k + b4.x; v.x = y >= 0.f ? y : LEAKY * y;
    m = tot[c4 + 1] * inv_n; var = tot[64 + c4 + 1] * inv_n - m * m;
    k = rsqrtf(var + BN_EPS) * g4.y;
    y = (v.y - m) * k + b4.y; v.y = y >= 0.f ? y : LEAKY * y;
    m = tot[c4 + 2] * inv_n; var = tot[64 + c4 + 2] * inv_n - m * m;
    k = rsqrtf(var + BN_EPS) * g4.z;
    y = (v.z - m) * k + b4.z; v.z = y >= 0.f ? y : LEAKY * y;
    m = tot[c4 + 3] * inv_n; var = tot[64 + c4 + 3] * inv_n - m * m;
    k = rsqrtf(var + BN_EPS) * g4.w;
    y = (v.w - m) * k + b4.w; v.w = y >= 0.f ? y : LEAKY * y;

    ((float4*)out)[gid] = v;
}

// ---------------------------------------------------------------------------
extern "C" void kernel_launch(void* const* d_in, const int* in_sizes, int n_in,
                              void* d_out, int out_size, void* d_ws, size_t ws_size,
                              hipStream_t stream) {
    const float* x     = (const float*)d_in[0];
    const int*   ei    = (const int*)d_in[1];
    const float* W     = (const float*)d_in[2];
    // d_in[3] = b: cancels in BatchNorm, unused.
    const float* gamma = (const float*)d_in[4];
    const float* beta  = (const float*)d_in[5];
    float* out = (float*)d_out;

    int n  = in_sizes[0] / C_IN;
    int nE = in_sizes[1] / 2;
    const int* rows = ei;
    const int* cols = ei + nE;
    int NB = (n + BSZ - 1) / BSZ;  // 391 for n=100k (<= NBMAX)

    // ws layout (srcs ALIASES pairs: binB sorts in place):
    // pd[n] int2 | xwsb[n*64] ushort | pairs/srcs[NB*CAP] | bfill[NBMAX] |
    // part[NPART*128] f32 | wb[8192] ushort
    int2* pd = (int2*)d_ws;
    unsigned short* xwsb = (unsigned short*)(pd + n);
    unsigned* pairs = (unsigned*)(xwsb + (size_t)n * C_OUT);
    int* srcs = (int*)pairs;
    int* bfill = (int*)(pairs + (size_t)NB * CAP);
    float* part = (float*)(bfill + NBMAX);
    unsigned short* wb = (unsigned short*)(part + NPART * 128);

    // 6 graph nodes: prep, binA, binB, gemm, gather(+stats), final
    k_prep<<<(C_IN * C_OUT + 255) / 256, 256, 0, stream>>>(W, wb, bfill, part);
    k_binA<<<(nE + CHUNKA - 1) / CHUNKA, 256, 0, stream>>>(rows, cols, bfill, pairs, nE, NB);
    k_binB<<<NB, 512, 0, stream>>>(bfill, pairs, pd, srcs, n);
    k_gemm<<<(n + 63) / 64, 256, 0, stream>>>(x, wb, pd, xwsb, n);
    k_gather<<<(n + 31) / 32, 256, 0, stream>>>(pd, srcs, xwsb, out, part, n);
    k_final<<<(n * (C_OUT / 4) + 255) / 256, 256, 0, stream>>>(part, gamma, beta, out, n);
}